// Round 5
// baseline (913.794 us; speedup 1.0000x reference)
//
#include <hip/hip_runtime.h>
#include <hip/hip_bf16.h>

#define DEV __device__ __forceinline__

constexpr int BATCH_ = 4;
constexpr int N1_ = 131072;
constexpr int N2_ = 32768;
constexpr int L1_ = N1_ / BATCH_;   // 32768
constexpr int L2_ = N2_ / BATCH_;   // 8192
constexpr int DM_ = 128;
constexpr int DI_ = 256;
constexpr int DS_ = 16;
constexpr int DTR_ = 8;
constexpr int TOT_ = N1_ + N2_;     // 163840

constexpr int TA_ = 32;             // phase A / final tile (tokens)
constexpr int TAH_ = TA_ + 3;       // + conv halo
constexpr int NTILE1_ = L1_ / TA_;  // 1024
constexpr int NTILE2_ = L2_ / TA_;  // 256
constexpr int NTILES_ = 4 * NTILE1_ + 4 * NTILE2_;  // 5120

constexpr int TS_ = 64;             // scan chunk length (64: 2560 chunks fills the GPU)
constexpr int NCH1_ = L1_ / TS_;    // 512
constexpr int NCH2_ = L2_ / TS_;    // 128
constexpr int NCHUNKS_ = 4 * NCH1_ + 4 * NCH2_;     // 2560

// radix sort: 10-bit digits, 3 passes, 1024-elem tiles
constexpr int NST_ = 160;           // 4*32 + 4*8 sort tiles

// padded permuted-sequence buffer (bf16 rows of 128)
constexpr int PADR_ = 16;                    // zero rows front/back per segment
constexpr int SR1_ = L1_ + 2 * PADR_;        // 32800 rows per s1 segment
constexpr int SR2_ = L2_ + 2 * PADR_;        // 8224 rows per s2 segment
constexpr int RTOT_ = 4 * SR1_ + 4 * SR2_;   // 164096 rows

// bf16 weight arena offsets (elements)
constexpr int IN1_OFF = 0;          // in_w model1 [512][128]
constexpr int IN2_OFF = 65536;
constexpr int XP1_OFF = 131072;     // xproj padded [48][256]
constexpr int XP2_OFF = 143360;
constexpr int OW1_OFF = 155648;     // out_w [128][256]
constexpr int OW2_OFF = 188416;
constexpr int W16_TOT = 221184;

typedef short short8 __attribute__((ext_vector_type(8)));
typedef float f32x4 __attribute__((ext_vector_type(4)));

struct MP {
  const float* ln_g; const float* ln_b; const float* in_w;
  const float* conv_w; const float* conv_b; const float* xproj_w;
  const float* dtproj_w; const float* dtproj_b; const float* A_log;
  const float* Dp; const float* out_w;
};

DEV float softplusf(float x) {
  // max(x,0) + log(1 + exp(-|x|)) using fast-log (no libm log1pf slow path)
  return fmaxf(x, 0.f) + __logf(1.f + __expf(-fabsf(x)));
}

DEV unsigned short f2bf(float f) {
  unsigned u = __builtin_bit_cast(unsigned, f);
  u += 0x7fffu + ((u >> 16) & 1u);
  return (unsigned short)(u >> 16);
}
DEV float bf2f(unsigned short s) {
  unsigned u = ((unsigned)s) << 16;
  return __builtin_bit_cast(float, u);
}

DEV void sort_tile_info(int tile, int& seg, int& tis, int& slotbase) {
  if (tile < 128) { seg = tile >> 5; tis = tile & 31; slotbase = seg * L1_; }
  else { seg = 4 + ((tile - 128) >> 3); tis = (tile - 128) & 7; slotbase = N1_ + (seg - 4) * L2_; }
}

// ---------------------------------------------------------------------------
// Weight prep: fp32 -> bf16 copies (xproj padded 40->48 rows with zeros).
// ---------------------------------------------------------------------------
__global__ __launch_bounds__(256) void k_prep(
    const float* __restrict__ in_w1, const float* __restrict__ xp1,
    const float* __restrict__ ow1,
    const float* __restrict__ in_w2, const float* __restrict__ xp2,
    const float* __restrict__ ow2,
    unsigned short* __restrict__ w16)
{
  const int i = blockIdx.x * 256 + threadIdx.x;
  if (i >= W16_TOT) return;
  float v;
  if (i < IN2_OFF) v = in_w1[i - IN1_OFF];
  else if (i < XP1_OFF) v = in_w2[i - IN2_OFF];
  else if (i < XP2_OFF) {
    const int j = i - XP1_OFF; const int r = j >> 8;
    v = (r < 40) ? xp1[j] : 0.f;
  } else if (i < OW1_OFF) {
    const int j = i - XP2_OFF; const int r = j >> 8;
    v = (r < 40) ? xp2[j] : 0.f;
  } else if (i < OW2_OFF) v = ow1[i - OW1_OFF];
  else v = ow2[i - OW2_OFF];
  w16[i] = f2bf(v);
}

// ---------------------------------------------------------------------------
// Radix sort pass kernels (stable, 10-bit digits).
// ---------------------------------------------------------------------------
__global__ __launch_bounds__(256) void k_hist(
    const int* __restrict__ hil1, const int* __restrict__ hil2,
    const unsigned* __restrict__ ksrc, unsigned* __restrict__ histg,
    int shift, int pass0)
{
  const int tile = blockIdx.x;
  int seg, tis, slotbase;
  sort_tile_info(tile, seg, tis, slotbase);
  const int tid = threadIdx.x;
  __shared__ unsigned h[1024];
  #pragma unroll
  for (int i = 0; i < 4; ++i) h[i * 256 + tid] = 0;
  __syncthreads();
  #pragma unroll
  for (int it = 0; it < 4; ++it) {
    const int li = tis * 1024 + it * 256 + tid;
    unsigned k;
    if (pass0) k = (unsigned)(seg < 4 ? hil1[seg * L1_ + li] : hil2[(seg - 4) * L2_ + li]);
    else       k = ksrc[slotbase + li];
    atomicAdd(&h[(k >> shift) & 1023u], 1u);
  }
  __syncthreads();
  #pragma unroll
  for (int i = 0; i < 4; ++i)
    histg[tile * 1024 + i * 256 + tid] = h[i * 256 + tid];
}

__global__ __launch_bounds__(256) void k_scanoff(
    const unsigned* __restrict__ histg, unsigned* __restrict__ offg)
{
  const int seg = blockIdx.x;
  const int ntiles = seg < 4 ? 32 : 8;
  const int tilebase = seg < 4 ? seg * 32 : 128 + (seg - 4) * 8;
  const int tid = threadIdx.x;
  const int d0 = tid * 4;
  unsigned tot[4] = {0, 0, 0, 0};
  for (int t = 0; t < ntiles; ++t) {
    const unsigned* hp = &histg[(size_t)(tilebase + t) * 1024 + d0];
    tot[0] += hp[0]; tot[1] += hp[1]; tot[2] += hp[2]; tot[3] += hp[3];
  }
  unsigned lp[4]; unsigned s = 0;
  #pragma unroll
  for (int j = 0; j < 4; ++j) { lp[j] = s; s += tot[j]; }
  const int lane = tid & 63, wv = tid >> 6;
  unsigned inc = s;
  #pragma unroll
  for (int off = 1; off < 64; off <<= 1) {
    unsigned v = (unsigned)__shfl_up((int)inc, off, 64);
    if (lane >= off) inc += v;
  }
  __shared__ unsigned wsum[4];
  if (lane == 63) wsum[wv] = inc;
  __syncthreads();
  unsigned wbase = 0;
  for (int w = 0; w < 4; ++w) if (w < wv) wbase += wsum[w];
  const unsigned base = wbase + inc - s;   // exclusive over threads
  #pragma unroll
  for (int j = 0; j < 4; ++j) {
    unsigned run = base + lp[j];
    for (int t = 0; t < ntiles; ++t) {
      offg[(size_t)(tilebase + t) * 1024 + d0 + j] = run;
      run += histg[(size_t)(tilebase + t) * 1024 + d0 + j];
    }
  }
}

__global__ __launch_bounds__(256) void k_scatter(
    const int* __restrict__ hil1, const int* __restrict__ hil2,
    const unsigned* __restrict__ ksrc, const int* __restrict__ isrc,
    const unsigned* __restrict__ offg,
    unsigned* __restrict__ kdst, int* __restrict__ idst,
    int* __restrict__ o_all, int shift, int pass0, int last)
{
  const int tile = blockIdx.x;
  int seg, tis, slotbase;
  sort_tile_info(tile, seg, tis, slotbase);
  const int tid = threadIdx.x;
  const int lane = tid & 63, wv = tid >> 6;
  __shared__ unsigned runb[1024];
  __shared__ unsigned wcnt[4 * 1024];
  #pragma unroll
  for (int i = 0; i < 4; ++i) runb[i * 256 + tid] = offg[(size_t)tile * 1024 + i * 256 + tid];
  #pragma unroll
  for (int it = 0; it < 4; ++it) {
    #pragma unroll
    for (int i = 0; i < 16; ++i) wcnt[i * 256 + tid] = 0;
    __syncthreads();
    const int li = tis * 1024 + it * 256 + tid;
    unsigned k; int v;
    if (pass0) {
      k = (unsigned)(seg < 4 ? hil1[seg * L1_ + li] : hil2[(seg - 4) * L2_ + li]);
      v = li;
    } else {
      k = ksrc[slotbase + li]; v = isrc[slotbase + li];
    }
    const unsigned d = (k >> shift) & 1023u;
    unsigned long long m = ~0ull;
    #pragma unroll
    for (int b = 0; b < 10; ++b) {
      const unsigned long long bb = __ballot((int)((d >> b) & 1u));
      m &= ((d >> b) & 1u) ? bb : ~bb;
    }
    const unsigned lrank = (unsigned)__popcll(m & ((1ull << lane) - 1ull));
    wcnt[wv * 1024 + d] = (unsigned)__popcll(m);
    __syncthreads();
    unsigned prior = runb[d];
    for (int w = 0; w < 3; ++w) if (w < wv) prior += wcnt[w * 1024 + d];
    const unsigned pos = prior + lrank;
    if (last) o_all[slotbase + pos] = v;
    else { kdst[slotbase + pos] = k; idst[slotbase + pos] = v; }
    __syncthreads();
    #pragma unroll
    for (int i = 0; i < 4; ++i) {
      const int dd = i * 256 + tid;
      runb[dd] += wcnt[dd] + wcnt[1024 + dd] + wcnt[2048 + dd] + wcnt[3072 + dd];
    }
    __syncthreads();
  }
}

// ---------------------------------------------------------------------------
// Gather: permute + positional embed + LayerNorm -> padded bf16 sequence.
// ---------------------------------------------------------------------------
__global__ __launch_bounds__(256) void k_gather(
    const float* __restrict__ feats1, const float* __restrict__ feats2,
    const float* __restrict__ pos1, const float* __restrict__ pos2,
    const float* __restrict__ pe_w, const float* __restrict__ pe_b,
    MP p1, MP p2, const int* __restrict__ o_all,
    unsigned* __restrict__ seq_g)
{
  const int wv = threadIdx.x >> 6, lane = threadIdx.x & 63;
  const int prow = blockIdx.x * 4 + wv;
  if (prow >= RTOT_) return;
  int seg, within;
  if (prow < 4 * SR1_) { seg = prow / SR1_; within = prow - seg * SR1_; }
  else { const int r = prow - 4 * SR1_; seg = 4 + r / SR2_; within = r - (seg - 4) * SR2_; }
  const bool is1 = seg < 4;
  const int b = is1 ? seg : seg - 4;
  const int L = is1 ? L1_ : L2_;
  const int p = within - PADR_;
  unsigned outw = 0;
  if (p >= 0 && p < L) {
    const int slotbase = is1 ? b * L1_ : N1_ + b * L2_;
    const int orig = o_all[slotbase + p];
    const MP P = is1 ? p2 : p1;     // s1 uses m2 params, s2 uses m1
    const float* fr = (is1 ? feats1 + (size_t)b * L1_ * DM_
                           : feats2 + (size_t)b * L2_ * DM_) + (size_t)orig * DM_;
    const float* pr = (is1 ? pos1 + (size_t)b * L1_ * 3
                           : pos2 + (size_t)b * L2_ * 3) + (size_t)orig * 3;
    const int c0 = 2 * lane;
    const float2 f = *(const float2*)(fr + c0);
    const float q0 = pr[0], q1 = pr[1], q2 = pr[2];
    float x0 = f.x + q0 * pe_w[c0 * 3 + 0] + q1 * pe_w[c0 * 3 + 1] + q2 * pe_w[c0 * 3 + 2] + pe_b[c0];
    float x1 = f.y + q0 * pe_w[c0 * 3 + 3] + q1 * pe_w[c0 * 3 + 4] + q2 * pe_w[c0 * 3 + 5] + pe_b[c0 + 1];
    float s = x0 + x1, qq = x0 * x0 + x1 * x1;
    #pragma unroll
    for (int off = 32; off; off >>= 1) {
      s += __shfl_xor(s, off, 64);
      qq += __shfl_xor(qq, off, 64);
    }
    const float mu = s * (1.f / 128.f);
    const float rs = rsqrtf(qq * (1.f / 128.f) - mu * mu + 1e-5f);
    const unsigned short o0 = f2bf((x0 - mu) * rs * P.ln_g[c0]     + P.ln_b[c0]);
    const unsigned short o1 = f2bf((x1 - mu) * rs * P.ln_g[c0 + 1] + P.ln_b[c0 + 1]);
    outw = (unsigned)o0 | ((unsigned)o1 << 16);
  }
  seq_g[(size_t)prow * 64 + lane] = outw;
}

// ---------------------------------------------------------------------------
// Phase A: coalesced-stage seq tile -> LDS, in_proj (MFMA) -> conv+silu
// IN PLACE -> x_proj (MFMA). The z half of in_proj is stored as silu(z)
// (scan3 then just multiplies — saves exp+rcp per scan step).
// ---------------------------------------------------------------------------
constexpr int HB_ = 136;    // hb16 ushort stride
constexpr int XB_ = 264;    // xcb16 ushort stride
constexpr int OFF_HB16 = TAH_ * XB_ * 2;         // 18480
constexpr int SMEM_A = OFF_HB16 + 48 * HB_ * 2;  // 31536

__global__ __launch_bounds__(256) void k_phaseA(
    MP p1, MP p2,
    const unsigned short* __restrict__ seq_g,
    const unsigned short* __restrict__ w16,
    __hip_bfloat16* __restrict__ xc_g, __hip_bfloat16* __restrict__ z_g,
    float* __restrict__ dbl_g)
{
  const int blk = blockIdx.x;
  bool is1; int b, tile;
  if (blk < 4 * NTILE1_) { is1 = true; b = blk / NTILE1_; tile = blk % NTILE1_; }
  else { const int r = blk - 4 * NTILE1_; is1 = false; b = r / NTILE2_; tile = r % NTILE2_; }
  const int slotbase = is1 ? b * L1_ : N1_ + b * L2_;
  const MP P = is1 ? p2 : p1;       // s1 uses m2 params, s2 uses m1
  const unsigned short* iw16 = w16 + (is1 ? IN2_OFF : IN1_OFF);
  const unsigned short* xp16 = w16 + (is1 ? XP2_OFF : XP1_OFF);
  const int segrow0 = is1 ? b * SR1_ : 4 * SR1_ + b * SR2_;
  const unsigned short* seq = seq_g + (size_t)segrow0 * DM_;   // row PADR_+p == token p
  const bool rev = is1;             // s1 runs reversed
  const int t0 = tile * TA_;
  const int pstart = rev ? t0 : t0 - 3;
  const int lsh = rev ? 0 : 3;

  __shared__ char smem[SMEM_A];
  unsigned short* xcb16 = (unsigned short*)smem;              // [35][264]; conv out in place
  unsigned short* hb16 = (unsigned short*)(smem + OFF_HB16);  // [48][136]
  unsigned short* xc16 = xcb16;                               // alias after conv

  const int tid = threadIdx.x;
  const int lane = tid & 63, wv = tid >> 6;
  const int l15 = lane & 15, quad = lane >> 4;

  // P0: zero MFMA pad rows 35..47; coalesced copy of 35 contiguous seq rows.
  {
    unsigned* hz = (unsigned*)hb16;
    for (int i = tid; i < 13 * (HB_ / 2); i += 256)
      hz[TAH_ * (HB_ / 2) + i] = 0;
    const unsigned short* src = seq + (size_t)(PADR_ + pstart) * DM_;
    #pragma unroll
    for (int i = tid; i < TAH_ * 16; i += 256) {
      const int r = i >> 4, c = (i & 15) * 8;
      *(uint4*)(hb16 + r * HB_ + c) = *(const uint4*)(src + (size_t)r * DM_ + c);
    }
  }
  __syncthreads();
  // P2: in_proj via MFMA. C[48x512] = hb16[48x128] @ in_w^T.
  {
    short8 afr[3][4];
    #pragma unroll
    for (int mt = 0; mt < 3; ++mt)
      #pragma unroll
      for (int t = 0; t < 4; ++t)
        afr[mt][t] = *(const short8*)(hb16 + (mt * 16 + l15) * HB_ + t * 32 + quad * 8);
    for (int nn = 0; nn < 8; ++nn) {
      const int ntile = nn * 4 + wv;
      f32x4 acc[3];
      #pragma unroll
      for (int mt = 0; mt < 3; ++mt) acc[mt] = (f32x4){0.f, 0.f, 0.f, 0.f};
      #pragma unroll
      for (int t = 0; t < 4; ++t) {
        const short8 bfr = *(const short8*)(iw16 + (size_t)(ntile * 16 + l15) * DM_ + t * 32 + quad * 8);
        #pragma unroll
        for (int mt = 0; mt < 3; ++mt)
          acc[mt] = __builtin_amdgcn_mfma_f32_16x16x32_bf16(afr[mt][t], bfr, acc[mt], 0, 0, 0);
      }
      const int col = ntile * 16 + l15;
      if (col < 256) {
        #pragma unroll
        for (int mt = 0; mt < 3; ++mt)
          #pragma unroll
          for (int r = 0; r < 4; ++r) {
            const int row = mt * 16 + quad * 4 + r;
            if (row < TAH_) xcb16[row * XB_ + col] = f2bf(acc[mt][r]);
          }
      } else {
        #pragma unroll
        for (int mt = 0; mt < 3; ++mt)
          #pragma unroll
          for (int r = 0; r < 4; ++r) {
            const int row = mt * 16 + quad * 4 + r;
            const int m = row - lsh;
            if (m >= 0 && m < TA_) {
              const float zz = acc[mt][r];
              const float sg = zz / (1.f + __expf(-zz));   // silu(z) precomputed
              z_g[(size_t)(slotbase + t0 + m) * DI_ + (col - 256)] = __float2bfloat16(sg);
            }
          }
      }
    }
  }
  __syncthreads();
  // P3: depthwise causal conv (dir-flipped for rev) + bias + silu -> xc_g,
  // and IN PLACE into xcb16 rows 0..31.
  {
    const int d = tid;
    const float w0 = P.conv_w[d * 4 + 0], w1 = P.conv_w[d * 4 + 1],
                w2 = P.conv_w[d * 4 + 2], w3 = P.conv_w[d * 4 + 3];
    const float cb = P.conv_b[d];
    float x0 = bf2f(xcb16[0 * XB_ + d]), x1 = bf2f(xcb16[1 * XB_ + d]),
          x2 = bf2f(xcb16[2 * XB_ + d]);
    #pragma unroll
    for (int m = 0; m < TA_; ++m) {
      const float x3 = bf2f(xcb16[(m + 3) * XB_ + d]);
      float v;
      if (rev) v = w3 * x0 + w2 * x1 + w1 * x2 + w0 * x3;
      else     v = w0 * x0 + w1 * x1 + w2 * x2 + w3 * x3;
      v += cb;
      v = v * (1.f / (1.f + __expf(-v)));
      const unsigned short vb = f2bf(v);
      xc_g[(size_t)(slotbase + t0 + m) * DI_ + d] = __builtin_bit_cast(__hip_bfloat16, vb);
      xcb16[m * XB_ + d] = vb;
      x0 = x1; x1 = x2; x2 = x3;
    }
  }
  __syncthreads();
  // P4: x_proj via MFMA. dbl[32x40] = xc16[32x256] @ xproj_w^T. Waves 0-2.
  if (wv < 3) {
    f32x4 acc0 = (f32x4){0.f,0.f,0.f,0.f}, acc1 = acc0;
    #pragma unroll
    for (int t = 0; t < 8; ++t) {
      const short8 bfr = *(const short8*)(xp16 + (size_t)(wv * 16 + l15) * DI_ + t * 32 + quad * 8);
      const short8 a0 = *(const short8*)(xc16 + (l15) * XB_ + t * 32 + quad * 8);
      const short8 a1 = *(const short8*)(xc16 + (16 + l15) * XB_ + t * 32 + quad * 8);
      acc0 = __builtin_amdgcn_mfma_f32_16x16x32_bf16(a0, bfr, acc0, 0, 0, 0);
      acc1 = __builtin_amdgcn_mfma_f32_16x16x32_bf16(a1, bfr, acc1, 0, 0, 0);
    }
    const int col = wv * 16 + l15;
    if (col < 40) {
      #pragma unroll
      for (int r = 0; r < 4; ++r) {
        dbl_g[(size_t)(slotbase + t0 + quad * 4 + r) * 40 + col] = acc0[r];
        dbl_g[(size_t)(slotbase + t0 + 16 + quad * 4 + r) * 40 + col] = acc1[r];
      }
    }
  }
}

// ---------------------------------------------------------------------------
// Scan helpers: load per-thread params, check A[s] = (s+1)*A0 structure.
// ---------------------------------------------------------------------------
struct ScanP {
  float Av[DS_]; float A0; bool fast;
  float dtw[DTR_]; float dtb;
};
DEV void load_scanp(const MP& P, int d, ScanP& sp) {
  #pragma unroll
  for (int s = 0; s < DS_; ++s) sp.Av[s] = -__expf(P.A_log[d * DS_ + s]);
  sp.A0 = sp.Av[0];
  bool f = true;
  #pragma unroll
  for (int s = 0; s < DS_; ++s)
    f = f && (fabsf(sp.Av[s] - (float)(s + 1) * sp.A0) <= 1e-3f * (float)(s + 1));
  sp.fast = f;
  #pragma unroll
  for (int r = 0; r < DTR_; ++r) sp.dtw[r] = P.dtproj_w[d * DTR_ + r];
  sp.dtb = P.dtproj_b[d];
}
DEV float dt_from(const float4& q0, const float4& q1, const ScanP& sp) {
  const float dtraw = sp.dtb
      + q0.x*sp.dtw[0] + q0.y*sp.dtw[1] + q0.z*sp.dtw[2] + q0.w*sp.dtw[3]
      + q1.x*sp.dtw[4] + q1.y*sp.dtw[5] + q1.z*sp.dtw[6] + q1.w*sp.dtw[7];
  return softplusf(dtraw);
}

// ---------------------------------------------------------------------------
// Scan pass 1: per-chunk local state (h0=0) + sum(dt). 1 block per chunk, d=tid.
// ---------------------------------------------------------------------------
__global__ __launch_bounds__(256) void k_scan1(
    MP p1, MP p2,
    const __hip_bfloat16* __restrict__ xc_g, const float* __restrict__ dbl_g,
    float* __restrict__ hloc, float* __restrict__ sumdt_g)
{
  const int blk = blockIdx.x;
  bool is1; int b, pc;
  if (blk < 4 * NCH1_) { is1 = true; b = blk / NCH1_; pc = blk % NCH1_; }
  else { const int r = blk - 4 * NCH1_; is1 = false; b = r / NCH2_; pc = r % NCH2_; }
  const MP P = is1 ? p2 : p1;
  const int L = is1 ? L1_ : L2_;
  const bool rev = is1;
  const int slotbase = is1 ? b * L1_ : N1_ + b * L2_;
  const int d = threadIdx.x;
  ScanP sp; load_scanp(P, d, sp);
  const unsigned short* xcp = (const unsigned short*)xc_g;
  float h[DS_];
  #pragma unroll
  for (int s = 0; s < DS_; ++s) h[s] = 0.f;
  float sdt = 0.f;
  const int s0 = rev ? (L - (pc + 1) * TS_) : pc * TS_;
  const int dp = rev ? -1 : 1;
  int slot = slotbase + (rev ? (s0 + TS_ - 1) : s0);
  if (sp.fast) {
    #pragma unroll 2
    for (int i = 0; i < TS_; ++i) {
      const float* dr = dbl_g + (size_t)slot * 40;
      const float4 q0 = *(const float4*)dr, q1 = *(const float4*)(dr + 4);
      const float u = bf2f(xcp[(size_t)slot * DI_ + d]);
      float4 Bv[4];
      #pragma unroll
      for (int j = 0; j < 4; ++j) Bv[j] = *(const float4*)(dr + 8 + 4 * j);
      const float dt = dt_from(q0, q1, sp);
      const float du = dt * u;
      sdt += dt;
      const float e1 = __expf(dt * sp.A0);
      const float e2 = e1 * e1, e3 = e2 * e1, e4 = e2 * e2;
      float base = 1.f;
      #pragma unroll
      for (int j = 0; j < 4; ++j) {
        const float m1 = base * e1, m2 = base * e2, m3 = base * e3, m4 = base * e4;
        h[4*j+0] = m1 * h[4*j+0] + du * Bv[j].x;
        h[4*j+1] = m2 * h[4*j+1] + du * Bv[j].y;
        h[4*j+2] = m3 * h[4*j+2] + du * Bv[j].z;
        h[4*j+3] = m4 * h[4*j+3] + du * Bv[j].w;
        base = m4;
      }
      slot += dp;
    }
  } else {
    for (int i = 0; i < TS_; ++i) {
      const float* dr = dbl_g + (size_t)slot * 40;
      const float4 q0 = *(const float4*)dr, q1 = *(const float4*)(dr + 4);
      const float dt = dt_from(q0, q1, sp);
      const float u = bf2f(xcp[(size_t)slot * DI_ + d]);
      const float du = dt * u;
      sdt += dt;
      float Bvv[16];
      #pragma unroll
      for (int j = 0; j < 4; ++j) *(float4*)&Bvv[4*j] = *(const float4*)(dr + 8 + 4*j);
      #pragma unroll
      for (int s = 0; s < DS_; ++s)
        h[s] = __expf(dt * sp.Av[s]) * h[s] + du * Bvv[s];
      slot += dp;
    }
  }
  float* hl = hloc + (size_t)blk * DS_ * DI_;
  #pragma unroll
  for (int s = 0; s < DS_; ++s) hl[s * DI_ + d] = h[s];
  sumdt_g[(size_t)blk * DI_ + d] = sdt;
}

// ---------------------------------------------------------------------------
// Scan pass 2: chain chunks IN PLACE. Reads hloc[idx] (local state), writes
// the incoming carry back to the same slot (scan3 reads it as h_in).
// ---------------------------------------------------------------------------
__global__ __launch_bounds__(256) void k_scan2(
    MP p1, MP p2, float* __restrict__ hloc,
    const float* __restrict__ sumdt_g)
{
  const int seq = blockIdx.x >> 4;
  const int s = blockIdx.x & 15;
  const bool is1 = seq < 4;
  const int b = is1 ? seq : seq - 4;
  const MP P = is1 ? p2 : p1;
  const int nch = is1 ? NCH1_ : NCH2_;
  const int chbase = is1 ? b * NCH1_ : 4 * NCH1_ + b * NCH2_;
  const int d = threadIdx.x;
  const float A = -__expf(P.A_log[d * DS_ + s]);
  float carry = 0.f;
  for (int pc = 0; pc < nch; ++pc) {
    const size_t idx = (size_t)(chbase + pc);
    const float sdt = sumdt_g[idx * DI_ + d];
    const float hl = hloc[idx * DS_ * DI_ + s * DI_ + d];
    hloc[idx * DS_ * DI_ + s * DI_ + d] = carry;
    carry = __expf(A * sdt) * carry + hl;
  }
}

// ---------------------------------------------------------------------------
// Scan pass 3: replay chunk from h_in (in-place hloc), emit
// v = (y + xc*D)*sz (bf16), written IN PLACE over the sz (= silu(z)) buffer.
// ---------------------------------------------------------------------------
__global__ __launch_bounds__(256) void k_scan3(
    MP p1, MP p2,
    const __hip_bfloat16* __restrict__ xc_g, const float* __restrict__ dbl_g,
    const float* __restrict__ hin, __hip_bfloat16* zv_g)
{
  const int blk = blockIdx.x;
  bool is1; int b, pc;
  if (blk < 4 * NCH1_) { is1 = true; b = blk / NCH1_; pc = blk % NCH1_; }
  else { const int r = blk - 4 * NCH1_; is1 = false; b = r / NCH2_; pc = r % NCH2_; }
  const MP P = is1 ? p2 : p1;
  const int L = is1 ? L1_ : L2_;
  const bool rev = is1;
  const int slotbase = is1 ? b * L1_ : N1_ + b * L2_;
  const int d = threadIdx.x;
  ScanP sp; load_scanp(P, d, sp);
  const float Dp = P.Dp[d];
  const unsigned short* xcp = (const unsigned short*)xc_g;
  unsigned short* zvp = (unsigned short*)zv_g;
  float h[DS_];
  const float* hi = hin + (size_t)blk * DS_ * DI_;
  #pragma unroll
  for (int s = 0; s < DS_; ++s) h[s] = hi[s * DI_ + d];
  const int s0 = rev ? (L - (pc + 1) * TS_) : pc * TS_;
  const int dp = rev ? -1 : 1;
  int slot = slotbase + (rev ? (s0 + TS_ - 1) : s0);
  if (sp.fast) {
    float sz = bf2f(zvp[(size_t)slot * DI_ + d]);
    #pragma unroll 2
    for (int i = 0; i < TS_; ++i) {
      const int nslot = (i + 1 < TS_) ? slot + dp : slot;
      const float nsz = bf2f(zvp[(size_t)nslot * DI_ + d]);   // prefetch before store
      const float* dr = dbl_g + (size_t)slot * 40;
      const float4 q0 = *(const float4*)dr, q1 = *(const float4*)(dr + 4);
      const float u = bf2f(xcp[(size_t)slot * DI_ + d]);
      float4 Bv[4], Cv[4];
      #pragma unroll
      for (int j = 0; j < 4; ++j) {
        Bv[j] = *(const float4*)(dr + 8 + 4 * j);
        Cv[j] = *(const float4*)(dr + 24 + 4 * j);
      }
      const float dt = dt_from(q0, q1, sp);
      const float du = dt * u;
      const float e1 = __expf(dt * sp.A0);
      const float e2 = e1 * e1, e3 = e2 * e1, e4 = e2 * e2;
      float base = 1.f, y = 0.f;
      #pragma unroll
      for (int j = 0; j < 4; ++j) {
        const float m1 = base * e1, m2 = base * e2, m3 = base * e3, m4 = base * e4;
        h[4*j+0] = m1 * h[4*j+0] + du * Bv[j].x;  y += h[4*j+0] * Cv[j].x;
        h[4*j+1] = m2 * h[4*j+1] + du * Bv[j].y;  y += h[4*j+1] * Cv[j].y;
        h[4*j+2] = m3 * h[4*j+2] + du * Bv[j].z;  y += h[4*j+2] * Cv[j].z;
        h[4*j+3] = m4 * h[4*j+3] + du * Bv[j].w;  y += h[4*j+3] * Cv[j].w;
        base = m4;
      }
      zvp[(size_t)slot * DI_ + d] = f2bf((y + u * Dp) * sz);
      slot = nslot; sz = nsz;
    }
  } else {
    for (int i = 0; i < TS_; ++i) {
      const float* dr = dbl_g + (size_t)slot * 40;
      const float4 q0 = *(const float4*)dr, q1 = *(const float4*)(dr + 4);
      const float dt = dt_from(q0, q1, sp);
      const float u = bf2f(xcp[(size_t)slot * DI_ + d]);
      const float sz = bf2f(zvp[(size_t)slot * DI_ + d]);
      const float du = dt * u;
      float Bvv[16], Cvv[16];
      #pragma unroll
      for (int j = 0; j < 4; ++j) {
        *(float4*)&Bvv[4*j] = *(const float4*)(dr + 8 + 4*j);
        *(float4*)&Cvv[4*j] = *(const float4*)(dr + 24 + 4*j);
      }
      float y = 0.f;
      #pragma unroll
      for (int s = 0; s < DS_; ++s) {
        h[s] = __expf(dt * sp.Av[s]) * h[s] + du * Bvv[s];
        y += h[s] * Cvv[s];
      }
      zvp[(size_t)slot * DI_ + d] = f2bf((y + u * Dp) * sz);
      slot += dp;
    }
  }
}

// ---------------------------------------------------------------------------
// Final: out_proj MFMA (A-fragments straight from global); output LN; scatter.
// ---------------------------------------------------------------------------
constexpr int OB_ = 132;
__global__ __launch_bounds__(256) void k_final(
    const __hip_bfloat16* __restrict__ v_g, const int* __restrict__ o_all,
    const unsigned short* __restrict__ w16,
    const float* __restrict__ norm_g, const float* __restrict__ norm_b,
    const float* __restrict__ normb_g, const float* __restrict__ normb_b,
    float* __restrict__ out)
{
  const int blk = blockIdx.x;
  bool is1; int b, tile;
  if (blk < 4 * NTILE1_) { is1 = true; b = blk / NTILE1_; tile = blk % NTILE1_; }
  else { const int r = blk - 4 * NTILE1_; is1 = false; b = r / NTILE2_; tile = r % NTILE2_; }
  const unsigned short* W = w16 + (is1 ? OW2_OFF : OW1_OFF);
  const float* gg = is1 ? normb_g : norm_g;
  const float* gb = is1 ? normb_b : norm_b;
  const int slotbase = is1 ? b * L1_ : N1_ + b * L2_;
  const int t0 = tile * TA_;
  __shared__ float obuf[TA_ * OB_];          // 16896 B
  const int tid = threadIdx.x;
  const int lane = tid & 63, wv = tid >> 6;
  const int l15 = lane & 15, quad = lane >> 4;
  {
    const unsigned short* vp = (const unsigned short*)v_g + (size_t)(slotbase + t0) * DI_;
    f32x4 acc00 = (f32x4){0.f,0.f,0.f,0.f}, acc01 = acc00, acc10 = acc00, acc11 = acc00;
    #pragma unroll
    for (int t = 0; t < 8; ++t) {
      const short8 a0 = *(const short8*)(vp + (size_t)(l15) * DI_ + t * 32 + quad * 8);
      const short8 a1 = *(const short8*)(vp + (size_t)(16 + l15) * DI_ + t * 32 + quad * 8);
      const short8 b0 = *(const short8*)(W + (size_t)((wv) * 16 + l15) * DI_ + t * 32 + quad * 8);
      const short8 b1 = *(const short8*)(W + (size_t)((wv + 4) * 16 + l15) * DI_ + t * 32 + quad * 8);
      acc00 = __builtin_amdgcn_mfma_f32_16x16x32_bf16(a0, b0, acc00, 0, 0, 0);
      acc01 = __builtin_amdgcn_mfma_f32_16x16x32_bf16(a1, b0, acc01, 0, 0, 0);
      acc10 = __builtin_amdgcn_mfma_f32_16x16x32_bf16(a0, b1, acc10, 0, 0, 0);
      acc11 = __builtin_amdgcn_mfma_f32_16x16x32_bf16(a1, b1, acc11, 0, 0, 0);
    }
    const int col0 = wv * 16 + l15;
    const int col1 = (wv + 4) * 16 + l15;
    #pragma unroll
    for (int r = 0; r < 4; ++r) {
      obuf[(quad * 4 + r) * OB_ + col0] = acc00[r];
      obuf[(16 + quad * 4 + r) * OB_ + col0] = acc01[r];
      obuf[(quad * 4 + r) * OB_ + col1] = acc10[r];
      obuf[(16 + quad * 4 + r) * OB_ + col1] = acc11[r];
    }
  }
  __syncthreads();
  {
    for (int m = wv; m < TA_; m += 4) {
      float x0 = obuf[m * OB_ + lane], x1 = obuf[m * OB_ + lane + 64];
      float s = x0 + x1, q = x0 * x0 + x1 * x1;
      #pragma unroll
      for (int off = 32; off; off >>= 1) {
        s += __shfl_xor(s, off, 64);
        q += __shfl_xor(q, off, 64);
      }
      const float mu = s * (1.f / 128.f);
      const float rs = rsqrtf(q * (1.f / 128.f) - mu * mu + 1e-5f);
      const int orig = o_all[slotbase + t0 + m];
      float* orow = out + (size_t)(slotbase + orig) * DM_;
      orow[lane]      = (x0 - mu) * rs * gg[lane]      + gb[lane];
      orow[lane + 64] = (x1 - mu) * rs * gg[lane + 64] + gb[lane + 64];
    }
  }
}

// ---------------------------------------------------------------------------
extern "C" void kernel_launch(void* const* d_in, const int* in_sizes, int n_in,
                              void* d_out, int out_size, void* d_ws, size_t ws_size,
                              hipStream_t stream)
{
  (void)in_sizes; (void)n_in; (void)out_size; (void)ws_size;
  const float* feats1 = (const float*)d_in[0];
  const float* feats2 = (const float*)d_in[1];
  const float* pos1   = (const float*)d_in[2];
  const float* pos2   = (const float*)d_in[3];
  const int*   hil1   = (const int*)d_in[4];
  const int*   hil2   = (const int*)d_in[5];
  const float* pe_w   = (const float*)d_in[6];
  const float* pe_b   = (const float*)d_in[7];
  const float* norm_g  = (const float*)d_in[8];
  const float* norm_b  = (const float*)d_in[9];
  const float* normb_g = (const float*)d_in[10];
  const float* normb_b = (const float*)d_in[11];
  MP p1 { (const float*)d_in[12], (const float*)d_in[13], (const float*)d_in[14],
          (const float*)d_in[15], (const float*)d_in[16], (const float*)d_in[17],
          (const float*)d_in[18], (const float*)d_in[19], (const float*)d_in[20],
          (const float*)d_in[21], (const float*)d_in[22] };
  MP p2 { (const float*)d_in[23], (const float*)d_in[24], (const float*)d_in[25],
          (const float*)d_in[26], (const float*)d_in[27], (const float*)d_in[28],
          (const float*)d_in[29], (const float*)d_in[30], (const float*)d_in[31],
          (const float*)d_in[32], (const float*)d_in[33] };

  char* w = (char*)d_ws;
  auto take = [&](size_t bytes) -> char* {
    char* p = w; w += (bytes + 255) & ~(size_t)255; return p;
  };
  int* o_all = (int*)take((size_t)TOT_ * 4);
  // Union region: radix-sort temporaries (live only during sort) overlaid
  // with the padded seq buffer (written by k_gather, after sort completes).
  char* uni = take((size_t)RTOT_ * DM_ * 2);   // 42 MB >= 6*0.66 MB sort temps
  unsigned* kA = (unsigned*)(uni);
  int*      iA = (int*)     (uni + (size_t)TOT_ * 4);
  unsigned* kB = (unsigned*)(uni + (size_t)TOT_ * 8);
  int*      iB = (int*)     (uni + (size_t)TOT_ * 12);
  unsigned* histg = (unsigned*)(uni + (size_t)TOT_ * 16);
  unsigned* offg  = (unsigned*)(uni + (size_t)TOT_ * 16 + (size_t)NST_ * 1024 * 4);
  unsigned* seq = (unsigned*)uni;              // padded bf16 rows (after sort)
  __hip_bfloat16* xc = (__hip_bfloat16*)take((size_t)TOT_ * DI_ * 2);
  __hip_bfloat16* vzb = (__hip_bfloat16*)take((size_t)TOT_ * DI_ * 2);  // silu(z), then v
  float* dbl = (float*)take((size_t)TOT_ * 40 * 4);
  float* hloc = (float*)take((size_t)NCHUNKS_ * DS_ * DI_ * 4);  // local states, then h_in (in place)
  float* sdt  = (float*)take((size_t)NCHUNKS_ * DI_ * 4);
  unsigned short* w16 = (unsigned short*)take((size_t)W16_TOT * 2);

  hipLaunchKernelGGL(k_prep, dim3((W16_TOT + 255) / 256), dim3(256), 0, stream,
                     p1.in_w, p1.xproj_w, p1.out_w, p2.in_w, p2.xproj_w, p2.out_w, w16);
  // radix sort: 3 passes of (hist, scan, scatter)
  hipLaunchKernelGGL(k_hist, dim3(NST_), dim3(256), 0, stream,
                     hil1, hil2, kB, histg, 0, 1);
  hipLaunchKernelGGL(k_scanoff, dim3(8), dim3(256), 0, stream, histg, offg);
  hipLaunchKernelGGL(k_scatter, dim3(NST_), dim3(256), 0, stream,
                     hil1, hil2, kB, iB, offg, kB, iB, o_all, 0, 1, 0);
  hipLaunchKernelGGL(k_hist, dim3(NST_), dim3(256), 0, stream,
                     hil1, hil2, kB, histg, 10, 0);
  hipLaunchKernelGGL(k_scanoff, dim3(8), dim3(256), 0, stream, histg, offg);
  hipLaunchKernelGGL(k_scatter, dim3(NST_), dim3(256), 0, stream,
                     hil1, hil2, kB, iB, offg, kA, iA, o_all, 10, 0, 0);
  hipLaunchKernelGGL(k_hist, dim3(NST_), dim3(256), 0, stream,
                     hil1, hil2, kA, histg, 20, 0);
  hipLaunchKernelGGL(k_scanoff, dim3(8), dim3(256), 0, stream, histg, offg);
  hipLaunchKernelGGL(k_scatter, dim3(NST_), dim3(256), 0, stream,
                     hil1, hil2, kA, iA, offg, kB, iB, o_all, 20, 0, 1);

  hipLaunchKernelGGL(k_gather, dim3((RTOT_ + 3) / 4), dim3(256), 0, stream,
                     feats1, feats2, pos1, pos2, pe_w, pe_b, p1, p2, o_all, seq);
  hipLaunchKernelGGL(k_phaseA, dim3(NTILES_), dim3(256), 0, stream,
                     p1, p2, (const unsigned short*)seq, w16, xc, vzb, dbl);
  hipLaunchKernelGGL(k_scan1, dim3(NCHUNKS_), dim3(256), 0, stream,
                     p1, p2, xc, dbl, hloc, sdt);
  hipLaunchKernelGGL(k_scan2, dim3(128), dim3(256), 0, stream,
                     p1, p2, hloc, sdt);
  hipLaunchKernelGGL(k_scan3, dim3(NCHUNKS_), dim3(256), 0, stream,
                     p1, p2, xc, dbl, hloc, vzb);
  hipLaunchKernelGGL(k_final, dim3(NTILES_), dim3(256), 0, stream,
                     vzb, o_all, w16, norm_g, norm_b, normb_g, normb_b,
                     (float*)d_out);
}

// Round 6
// 799.574 us; speedup vs baseline: 1.1429x; 1.1429x over previous
//
#include <hip/hip_runtime.h>
#include <hip/hip_bf16.h>

#define DEV __device__ __forceinline__

constexpr int BATCH_ = 4;
constexpr int N1_ = 131072;
constexpr int N2_ = 32768;
constexpr int L1_ = N1_ / BATCH_;   // 32768
constexpr int L2_ = N2_ / BATCH_;   // 8192
constexpr int DM_ = 128;
constexpr int DI_ = 256;
constexpr int DS_ = 16;
constexpr int DTR_ = 8;
constexpr int TOT_ = N1_ + N2_;     // 163840

constexpr int TA_ = 32;             // phase A / final tile (tokens)
constexpr int TAH_ = TA_ + 3;       // + conv halo
constexpr int NTILE1_ = L1_ / TA_;  // 1024
constexpr int NTILE2_ = L2_ / TA_;  // 256
constexpr int NTILES_ = 4 * NTILE1_ + 4 * NTILE2_;  // 5120

constexpr int TS_ = 64;             // scan chunk length (2560 chunks fills the GPU)
constexpr int NCH1_ = L1_ / TS_;    // 512
constexpr int NCH2_ = L2_ / TS_;    // 128
constexpr int NCHUNKS_ = 4 * NCH1_ + 4 * NCH2_;     // 2560

// hierarchical chunk-chaining: 32-chunk groups
constexpr int GRP_ = 32;
constexpr int NG1_ = NCH1_ / GRP_;  // 16 groups per s1 sequence
constexpr int NG2_ = NCH2_ / GRP_;  // 4 groups per s2 sequence
constexpr int NGRPS_ = 4 * NG1_ + 4 * NG2_;  // 80

// radix sort: 10-bit digits, 3 passes, 1024-elem tiles
constexpr int NST_ = 160;           // 4*32 + 4*8 sort tiles

// padded permuted-sequence buffer (bf16 rows of 128)
constexpr int PADR_ = 16;                    // zero rows front/back per segment
constexpr int SR1_ = L1_ + 2 * PADR_;        // 32800 rows per s1 segment
constexpr int SR2_ = L2_ + 2 * PADR_;        // 8224 rows per s2 segment
constexpr int RTOT_ = 4 * SR1_ + 4 * SR2_;   // 164096 rows

// bf16 weight arena offsets (elements)
constexpr int IN1_OFF = 0;          // in_w model1 [512][128]
constexpr int IN2_OFF = 65536;
constexpr int XP1_OFF = 131072;     // xproj padded [48][256]
constexpr int XP2_OFF = 143360;
constexpr int OW1_OFF = 155648;     // out_w [128][256]
constexpr int OW2_OFF = 188416;
constexpr int W16_TOT = 221184;

typedef short short8 __attribute__((ext_vector_type(8)));
typedef float f32x4 __attribute__((ext_vector_type(4)));

struct MP {
  const float* ln_g; const float* ln_b; const float* in_w;
  const float* conv_w; const float* conv_b; const float* xproj_w;
  const float* dtproj_w; const float* dtproj_b; const float* A_log;
  const float* Dp; const float* out_w;
};

DEV float softplusf(float x) {
  // max(x,0) + log(1 + exp(-|x|)) using fast-log (no libm log1pf slow path)
  return fmaxf(x, 0.f) + __logf(1.f + __expf(-fabsf(x)));
}

DEV unsigned short f2bf(float f) {
  unsigned u = __builtin_bit_cast(unsigned, f);
  u += 0x7fffu + ((u >> 16) & 1u);
  return (unsigned short)(u >> 16);
}
DEV float bf2f(unsigned short s) {
  unsigned u = ((unsigned)s) << 16;
  return __builtin_bit_cast(float, u);
}

DEV void sort_tile_info(int tile, int& seg, int& tis, int& slotbase) {
  if (tile < 128) { seg = tile >> 5; tis = tile & 31; slotbase = seg * L1_; }
  else { seg = 4 + ((tile - 128) >> 3); tis = (tile - 128) & 7; slotbase = N1_ + (seg - 4) * L2_; }
}

DEV void group_info(int g, bool& is1, int& chbase) {
  if (g < 4 * NG1_) { is1 = true; chbase = (g >> 4) * NCH1_ + (g & 15) * GRP_; }
  else { const int r = g - 4 * NG1_; is1 = false; chbase = 4 * NCH1_ + (r >> 2) * NCH2_ + (r & 3) * GRP_; }
}

// ---------------------------------------------------------------------------
// Weight prep: fp32 -> bf16 copies (xproj padded 40->48 rows with zeros).
// ---------------------------------------------------------------------------
__global__ __launch_bounds__(256) void k_prep(
    const float* __restrict__ in_w1, const float* __restrict__ xp1,
    const float* __restrict__ ow1,
    const float* __restrict__ in_w2, const float* __restrict__ xp2,
    const float* __restrict__ ow2,
    unsigned short* __restrict__ w16)
{
  const int i = blockIdx.x * 256 + threadIdx.x;
  if (i >= W16_TOT) return;
  float v;
  if (i < IN2_OFF) v = in_w1[i - IN1_OFF];
  else if (i < XP1_OFF) v = in_w2[i - IN2_OFF];
  else if (i < XP2_OFF) {
    const int j = i - XP1_OFF; const int r = j >> 8;
    v = (r < 40) ? xp1[j] : 0.f;
  } else if (i < OW1_OFF) {
    const int j = i - XP2_OFF; const int r = j >> 8;
    v = (r < 40) ? xp2[j] : 0.f;
  } else if (i < OW2_OFF) v = ow1[i - OW1_OFF];
  else v = ow2[i - OW2_OFF];
  w16[i] = f2bf(v);
}

// ---------------------------------------------------------------------------
// Radix sort pass kernels (stable, 10-bit digits).
// ---------------------------------------------------------------------------
__global__ __launch_bounds__(256) void k_hist(
    const int* __restrict__ hil1, const int* __restrict__ hil2,
    const unsigned* __restrict__ ksrc, unsigned* __restrict__ histg,
    int shift, int pass0)
{
  const int tile = blockIdx.x;
  int seg, tis, slotbase;
  sort_tile_info(tile, seg, tis, slotbase);
  const int tid = threadIdx.x;
  __shared__ unsigned h[1024];
  #pragma unroll
  for (int i = 0; i < 4; ++i) h[i * 256 + tid] = 0;
  __syncthreads();
  #pragma unroll
  for (int it = 0; it < 4; ++it) {
    const int li = tis * 1024 + it * 256 + tid;
    unsigned k;
    if (pass0) k = (unsigned)(seg < 4 ? hil1[seg * L1_ + li] : hil2[(seg - 4) * L2_ + li]);
    else       k = ksrc[slotbase + li];
    atomicAdd(&h[(k >> shift) & 1023u], 1u);
  }
  __syncthreads();
  #pragma unroll
  for (int i = 0; i < 4; ++i)
    histg[tile * 1024 + i * 256 + tid] = h[i * 256 + tid];
}

__global__ __launch_bounds__(256) void k_scanoff(
    const unsigned* __restrict__ histg, unsigned* __restrict__ offg)
{
  const int seg = blockIdx.x;
  const int ntiles = seg < 4 ? 32 : 8;
  const int tilebase = seg < 4 ? seg * 32 : 128 + (seg - 4) * 8;
  const int tid = threadIdx.x;
  const int d0 = tid * 4;
  unsigned tot[4] = {0, 0, 0, 0};
  for (int t = 0; t < ntiles; ++t) {
    const unsigned* hp = &histg[(size_t)(tilebase + t) * 1024 + d0];
    tot[0] += hp[0]; tot[1] += hp[1]; tot[2] += hp[2]; tot[3] += hp[3];
  }
  unsigned lp[4]; unsigned s = 0;
  #pragma unroll
  for (int j = 0; j < 4; ++j) { lp[j] = s; s += tot[j]; }
  const int lane = tid & 63, wv = tid >> 6;
  unsigned inc = s;
  #pragma unroll
  for (int off = 1; off < 64; off <<= 1) {
    unsigned v = (unsigned)__shfl_up((int)inc, off, 64);
    if (lane >= off) inc += v;
  }
  __shared__ unsigned wsum[4];
  if (lane == 63) wsum[wv] = inc;
  __syncthreads();
  unsigned wbase = 0;
  for (int w = 0; w < 4; ++w) if (w < wv) wbase += wsum[w];
  const unsigned base = wbase + inc - s;   // exclusive over threads
  #pragma unroll
  for (int j = 0; j < 4; ++j) {
    unsigned run = base + lp[j];
    for (int t = 0; t < ntiles; ++t) {
      offg[(size_t)(tilebase + t) * 1024 + d0 + j] = run;
      run += histg[(size_t)(tilebase + t) * 1024 + d0 + j];
    }
  }
}

__global__ __launch_bounds__(256) void k_scatter(
    const int* __restrict__ hil1, const int* __restrict__ hil2,
    const unsigned* __restrict__ ksrc, const int* __restrict__ isrc,
    const unsigned* __restrict__ offg,
    unsigned* __restrict__ kdst, int* __restrict__ idst,
    int* __restrict__ o_all, int shift, int pass0, int last)
{
  const int tile = blockIdx.x;
  int seg, tis, slotbase;
  sort_tile_info(tile, seg, tis, slotbase);
  const int tid = threadIdx.x;
  const int lane = tid & 63, wv = tid >> 6;
  __shared__ unsigned runb[1024];
  __shared__ unsigned wcnt[4 * 1024];
  #pragma unroll
  for (int i = 0; i < 4; ++i) runb[i * 256 + tid] = offg[(size_t)tile * 1024 + i * 256 + tid];
  #pragma unroll
  for (int it = 0; it < 4; ++it) {
    #pragma unroll
    for (int i = 0; i < 16; ++i) wcnt[i * 256 + tid] = 0;
    __syncthreads();
    const int li = tis * 1024 + it * 256 + tid;
    unsigned k; int v;
    if (pass0) {
      k = (unsigned)(seg < 4 ? hil1[seg * L1_ + li] : hil2[(seg - 4) * L2_ + li]);
      v = li;
    } else {
      k = ksrc[slotbase + li]; v = isrc[slotbase + li];
    }
    const unsigned d = (k >> shift) & 1023u;
    unsigned long long m = ~0ull;
    #pragma unroll
    for (int b = 0; b < 10; ++b) {
      const unsigned long long bb = __ballot((int)((d >> b) & 1u));
      m &= ((d >> b) & 1u) ? bb : ~bb;
    }
    const unsigned lrank = (unsigned)__popcll(m & ((1ull << lane) - 1ull));
    wcnt[wv * 1024 + d] = (unsigned)__popcll(m);
    __syncthreads();
    unsigned prior = runb[d];
    for (int w = 0; w < 3; ++w) if (w < wv) prior += wcnt[w * 1024 + d];
    const unsigned pos = prior + lrank;
    if (last) o_all[slotbase + pos] = v;
    else { kdst[slotbase + pos] = k; idst[slotbase + pos] = v; }
    __syncthreads();
    #pragma unroll
    for (int i = 0; i < 4; ++i) {
      const int dd = i * 256 + tid;
      runb[dd] += wcnt[dd] + wcnt[1024 + dd] + wcnt[2048 + dd] + wcnt[3072 + dd];
    }
    __syncthreads();
  }
}

// ---------------------------------------------------------------------------
// Gather: permute + positional embed + LayerNorm -> padded bf16 sequence.
// ---------------------------------------------------------------------------
__global__ __launch_bounds__(256) void k_gather(
    const float* __restrict__ feats1, const float* __restrict__ feats2,
    const float* __restrict__ pos1, const float* __restrict__ pos2,
    const float* __restrict__ pe_w, const float* __restrict__ pe_b,
    MP p1, MP p2, const int* __restrict__ o_all,
    unsigned* __restrict__ seq_g)
{
  const int wv = threadIdx.x >> 6, lane = threadIdx.x & 63;
  const int prow = blockIdx.x * 4 + wv;
  if (prow >= RTOT_) return;
  int seg, within;
  if (prow < 4 * SR1_) { seg = prow / SR1_; within = prow - seg * SR1_; }
  else { const int r = prow - 4 * SR1_; seg = 4 + r / SR2_; within = r - (seg - 4) * SR2_; }
  const bool is1 = seg < 4;
  const int b = is1 ? seg : seg - 4;
  const int L = is1 ? L1_ : L2_;
  const int p = within - PADR_;
  unsigned outw = 0;
  if (p >= 0 && p < L) {
    const int slotbase = is1 ? b * L1_ : N1_ + b * L2_;
    const int orig = o_all[slotbase + p];
    const MP P = is1 ? p2 : p1;     // s1 uses m2 params, s2 uses m1
    const float* fr = (is1 ? feats1 + (size_t)b * L1_ * DM_
                           : feats2 + (size_t)b * L2_ * DM_) + (size_t)orig * DM_;
    const float* pr = (is1 ? pos1 + (size_t)b * L1_ * 3
                           : pos2 + (size_t)b * L2_ * 3) + (size_t)orig * 3;
    const int c0 = 2 * lane;
    const float2 f = *(const float2*)(fr + c0);
    const float q0 = pr[0], q1 = pr[1], q2 = pr[2];
    float x0 = f.x + q0 * pe_w[c0 * 3 + 0] + q1 * pe_w[c0 * 3 + 1] + q2 * pe_w[c0 * 3 + 2] + pe_b[c0];
    float x1 = f.y + q0 * pe_w[c0 * 3 + 3] + q1 * pe_w[c0 * 3 + 4] + q2 * pe_w[c0 * 3 + 5] + pe_b[c0 + 1];
    float s = x0 + x1, qq = x0 * x0 + x1 * x1;
    #pragma unroll
    for (int off = 32; off; off >>= 1) {
      s += __shfl_xor(s, off, 64);
      qq += __shfl_xor(qq, off, 64);
    }
    const float mu = s * (1.f / 128.f);
    const float rs = rsqrtf(qq * (1.f / 128.f) - mu * mu + 1e-5f);
    const unsigned short o0 = f2bf((x0 - mu) * rs * P.ln_g[c0]     + P.ln_b[c0]);
    const unsigned short o1 = f2bf((x1 - mu) * rs * P.ln_g[c0 + 1] + P.ln_b[c0 + 1]);
    outw = (unsigned)o0 | ((unsigned)o1 << 16);
  }
  seq_g[(size_t)prow * 64 + lane] = outw;
}

// ---------------------------------------------------------------------------
// Phase A: coalesced-stage seq tile -> LDS, in_proj (MFMA) -> conv+silu
// IN PLACE -> x_proj (MFMA). The z half of in_proj is stored as silu(z).
// ---------------------------------------------------------------------------
constexpr int HB_ = 136;    // hb16 ushort stride
constexpr int XB_ = 264;    // xcb16 ushort stride
constexpr int OFF_HB16 = TAH_ * XB_ * 2;         // 18480
constexpr int SMEM_A = OFF_HB16 + 48 * HB_ * 2;  // 31536

__global__ __launch_bounds__(256) void k_phaseA(
    MP p1, MP p2,
    const unsigned short* __restrict__ seq_g,
    const unsigned short* __restrict__ w16,
    __hip_bfloat16* __restrict__ xc_g, __hip_bfloat16* __restrict__ z_g,
    float* __restrict__ dbl_g)
{
  const int blk = blockIdx.x;
  bool is1; int b, tile;
  if (blk < 4 * NTILE1_) { is1 = true; b = blk / NTILE1_; tile = blk % NTILE1_; }
  else { const int r = blk - 4 * NTILE1_; is1 = false; b = r / NTILE2_; tile = r % NTILE2_; }
  const int slotbase = is1 ? b * L1_ : N1_ + b * L2_;
  const MP P = is1 ? p2 : p1;       // s1 uses m2 params, s2 uses m1
  const unsigned short* iw16 = w16 + (is1 ? IN2_OFF : IN1_OFF);
  const unsigned short* xp16 = w16 + (is1 ? XP2_OFF : XP1_OFF);
  const int segrow0 = is1 ? b * SR1_ : 4 * SR1_ + b * SR2_;
  const unsigned short* seq = seq_g + (size_t)segrow0 * DM_;   // row PADR_+p == token p
  const bool rev = is1;             // s1 runs reversed
  const int t0 = tile * TA_;
  const int pstart = rev ? t0 : t0 - 3;
  const int lsh = rev ? 0 : 3;

  __shared__ char smem[SMEM_A];
  unsigned short* xcb16 = (unsigned short*)smem;              // [35][264]; conv out in place
  unsigned short* hb16 = (unsigned short*)(smem + OFF_HB16);  // [48][136]
  unsigned short* xc16 = xcb16;                               // alias after conv

  const int tid = threadIdx.x;
  const int lane = tid & 63, wv = tid >> 6;
  const int l15 = lane & 15, quad = lane >> 4;

  // P0: zero MFMA pad rows 35..47; coalesced copy of 35 contiguous seq rows.
  {
    unsigned* hz = (unsigned*)hb16;
    for (int i = tid; i < 13 * (HB_ / 2); i += 256)
      hz[TAH_ * (HB_ / 2) + i] = 0;
    const unsigned short* src = seq + (size_t)(PADR_ + pstart) * DM_;
    #pragma unroll
    for (int i = tid; i < TAH_ * 16; i += 256) {
      const int r = i >> 4, c = (i & 15) * 8;
      *(uint4*)(hb16 + r * HB_ + c) = *(const uint4*)(src + (size_t)r * DM_ + c);
    }
  }
  __syncthreads();
  // P2: in_proj via MFMA. C[48x512] = hb16[48x128] @ in_w^T.
  {
    short8 afr[3][4];
    #pragma unroll
    for (int mt = 0; mt < 3; ++mt)
      #pragma unroll
      for (int t = 0; t < 4; ++t)
        afr[mt][t] = *(const short8*)(hb16 + (mt * 16 + l15) * HB_ + t * 32 + quad * 8);
    for (int nn = 0; nn < 8; ++nn) {
      const int ntile = nn * 4 + wv;
      f32x4 acc[3];
      #pragma unroll
      for (int mt = 0; mt < 3; ++mt) acc[mt] = (f32x4){0.f, 0.f, 0.f, 0.f};
      #pragma unroll
      for (int t = 0; t < 4; ++t) {
        const short8 bfr = *(const short8*)(iw16 + (size_t)(ntile * 16 + l15) * DM_ + t * 32 + quad * 8);
        #pragma unroll
        for (int mt = 0; mt < 3; ++mt)
          acc[mt] = __builtin_amdgcn_mfma_f32_16x16x32_bf16(afr[mt][t], bfr, acc[mt], 0, 0, 0);
      }
      const int col = ntile * 16 + l15;
      if (col < 256) {
        #pragma unroll
        for (int mt = 0; mt < 3; ++mt)
          #pragma unroll
          for (int r = 0; r < 4; ++r) {
            const int row = mt * 16 + quad * 4 + r;
            if (row < TAH_) xcb16[row * XB_ + col] = f2bf(acc[mt][r]);
          }
      } else {
        #pragma unroll
        for (int mt = 0; mt < 3; ++mt)
          #pragma unroll
          for (int r = 0; r < 4; ++r) {
            const int row = mt * 16 + quad * 4 + r;
            const int m = row - lsh;
            if (m >= 0 && m < TA_) {
              const float zz = acc[mt][r];
              const float sg = zz / (1.f + __expf(-zz));   // silu(z) precomputed
              z_g[(size_t)(slotbase + t0 + m) * DI_ + (col - 256)] = __float2bfloat16(sg);
            }
          }
      }
    }
  }
  __syncthreads();
  // P3: depthwise causal conv (dir-flipped for rev) + bias + silu -> xc_g,
  // and IN PLACE into xcb16 rows 0..31.
  {
    const int d = tid;
    const float w0 = P.conv_w[d * 4 + 0], w1 = P.conv_w[d * 4 + 1],
                w2 = P.conv_w[d * 4 + 2], w3 = P.conv_w[d * 4 + 3];
    const float cb = P.conv_b[d];
    float x0 = bf2f(xcb16[0 * XB_ + d]), x1 = bf2f(xcb16[1 * XB_ + d]),
          x2 = bf2f(xcb16[2 * XB_ + d]);
    #pragma unroll
    for (int m = 0; m < TA_; ++m) {
      const float x3 = bf2f(xcb16[(m + 3) * XB_ + d]);
      float v;
      if (rev) v = w3 * x0 + w2 * x1 + w1 * x2 + w0 * x3;
      else     v = w0 * x0 + w1 * x1 + w2 * x2 + w3 * x3;
      v += cb;
      v = v * (1.f / (1.f + __expf(-v)));
      const unsigned short vb = f2bf(v);
      xc_g[(size_t)(slotbase + t0 + m) * DI_ + d] = __builtin_bit_cast(__hip_bfloat16, vb);
      xcb16[m * XB_ + d] = vb;
      x0 = x1; x1 = x2; x2 = x3;
    }
  }
  __syncthreads();
  // P4: x_proj via MFMA. dbl[32x40] = xc16[32x256] @ xproj_w^T. Waves 0-2.
  if (wv < 3) {
    f32x4 acc0 = (f32x4){0.f,0.f,0.f,0.f}, acc1 = acc0;
    #pragma unroll
    for (int t = 0; t < 8; ++t) {
      const short8 bfr = *(const short8*)(xp16 + (size_t)(wv * 16 + l15) * DI_ + t * 32 + quad * 8);
      const short8 a0 = *(const short8*)(xc16 + (l15) * XB_ + t * 32 + quad * 8);
      const short8 a1 = *(const short8*)(xc16 + (16 + l15) * XB_ + t * 32 + quad * 8);
      acc0 = __builtin_amdgcn_mfma_f32_16x16x32_bf16(a0, bfr, acc0, 0, 0, 0);
      acc1 = __builtin_amdgcn_mfma_f32_16x16x32_bf16(a1, bfr, acc1, 0, 0, 0);
    }
    const int col = wv * 16 + l15;
    if (col < 40) {
      #pragma unroll
      for (int r = 0; r < 4; ++r) {
        dbl_g[(size_t)(slotbase + t0 + quad * 4 + r) * 40 + col] = acc0[r];
        dbl_g[(size_t)(slotbase + t0 + 16 + quad * 4 + r) * 40 + col] = acc1[r];
      }
    }
  }
}

// ---------------------------------------------------------------------------
// Scan helpers: load per-thread params, check A[s] = (s+1)*A0 structure.
// ---------------------------------------------------------------------------
struct ScanP {
  float Av[DS_]; float A0; bool fast;
  float dtw[DTR_]; float dtb;
};
DEV void load_scanp(const MP& P, int d, ScanP& sp) {
  #pragma unroll
  for (int s = 0; s < DS_; ++s) sp.Av[s] = -__expf(P.A_log[d * DS_ + s]);
  sp.A0 = sp.Av[0];
  bool f = true;
  #pragma unroll
  for (int s = 0; s < DS_; ++s)
    f = f && (fabsf(sp.Av[s] - (float)(s + 1) * sp.A0) <= 1e-3f * (float)(s + 1));
  sp.fast = f;
  #pragma unroll
  for (int r = 0; r < DTR_; ++r) sp.dtw[r] = P.dtproj_w[d * DTR_ + r];
  sp.dtb = P.dtproj_b[d];
}
DEV float dt_from(const float4& q0, const float4& q1, const ScanP& sp) {
  const float dtraw = sp.dtb
      + q0.x*sp.dtw[0] + q0.y*sp.dtw[1] + q0.z*sp.dtw[2] + q0.w*sp.dtw[3]
      + q1.x*sp.dtw[4] + q1.y*sp.dtw[5] + q1.z*sp.dtw[6] + q1.w*sp.dtw[7];
  return softplusf(dtraw);
}

// ---------------------------------------------------------------------------
// Scan pass 1: per-chunk local state (h0=0) + sum(dt). 1 block per chunk, d=tid.
// ---------------------------------------------------------------------------
__global__ __launch_bounds__(256) void k_scan1(
    MP p1, MP p2,
    const __hip_bfloat16* __restrict__ xc_g, const float* __restrict__ dbl_g,
    float* __restrict__ hloc, float* __restrict__ sumdt_g)
{
  const int blk = blockIdx.x;
  bool is1; int b, pc;
  if (blk < 4 * NCH1_) { is1 = true; b = blk / NCH1_; pc = blk % NCH1_; }
  else { const int r = blk - 4 * NCH1_; is1 = false; b = r / NCH2_; pc = r % NCH2_; }
  const MP P = is1 ? p2 : p1;
  const int L = is1 ? L1_ : L2_;
  const bool rev = is1;
  const int slotbase = is1 ? b * L1_ : N1_ + b * L2_;
  const int d = threadIdx.x;
  ScanP sp; load_scanp(P, d, sp);
  const unsigned short* xcp = (const unsigned short*)xc_g;
  float h[DS_];
  #pragma unroll
  for (int s = 0; s < DS_; ++s) h[s] = 0.f;
  float sdt = 0.f;
  const int s0 = rev ? (L - (pc + 1) * TS_) : pc * TS_;
  const int dp = rev ? -1 : 1;
  int slot = slotbase + (rev ? (s0 + TS_ - 1) : s0);
  if (sp.fast) {
    #pragma unroll 2
    for (int i = 0; i < TS_; ++i) {
      const float* dr = dbl_g + (size_t)slot * 40;
      const float4 q0 = *(const float4*)dr, q1 = *(const float4*)(dr + 4);
      const float u = bf2f(xcp[(size_t)slot * DI_ + d]);
      float4 Bv[4];
      #pragma unroll
      for (int j = 0; j < 4; ++j) Bv[j] = *(const float4*)(dr + 8 + 4 * j);
      const float dt = dt_from(q0, q1, sp);
      const float du = dt * u;
      sdt += dt;
      const float e1 = __expf(dt * sp.A0);
      const float e2 = e1 * e1, e3 = e2 * e1, e4 = e2 * e2;
      float base = 1.f;
      #pragma unroll
      for (int j = 0; j < 4; ++j) {
        const float m1 = base * e1, m2 = base * e2, m3 = base * e3, m4 = base * e4;
        h[4*j+0] = m1 * h[4*j+0] + du * Bv[j].x;
        h[4*j+1] = m2 * h[4*j+1] + du * Bv[j].y;
        h[4*j+2] = m3 * h[4*j+2] + du * Bv[j].z;
        h[4*j+3] = m4 * h[4*j+3] + du * Bv[j].w;
        base = m4;
      }
      slot += dp;
    }
  } else {
    for (int i = 0; i < TS_; ++i) {
      const float* dr = dbl_g + (size_t)slot * 40;
      const float4 q0 = *(const float4*)dr, q1 = *(const float4*)(dr + 4);
      const float dt = dt_from(q0, q1, sp);
      const float u = bf2f(xcp[(size_t)slot * DI_ + d]);
      const float du = dt * u;
      sdt += dt;
      float Bvv[16];
      #pragma unroll
      for (int j = 0; j < 4; ++j) *(float4*)&Bvv[4*j] = *(const float4*)(dr + 8 + 4*j);
      #pragma unroll
      for (int s = 0; s < DS_; ++s)
        h[s] = __expf(dt * sp.Av[s]) * h[s] + du * Bvv[s];
      slot += dp;
    }
  }
  float* hl = hloc + (size_t)blk * DS_ * DI_;
  #pragma unroll
  for (int s = 0; s < DS_; ++s) hl[s * DI_ + d] = h[s];
  sumdt_g[(size_t)blk * DI_ + d] = sdt;
}

// ---------------------------------------------------------------------------
// Scan pass 2a: group-local chaining IN PLACE (carry0 = 0 per group).
// Grid = NGRPS_ x DS_ (1280 blocks, 10x the old serial scan2's parallelism).
// Writes group carry-out Sg; the s==0 block also emits presum (prefix sum of
// sumdt within group, per chunk) and gsum (group total) as a free byproduct.
// ---------------------------------------------------------------------------
__global__ __launch_bounds__(256) void k_scan2a(
    MP p1, MP p2, float* __restrict__ hloc,
    const float* __restrict__ sumdt_g,
    float* __restrict__ Sg, float* __restrict__ presum_g,
    float* __restrict__ gsum_g)
{
  const int g = blockIdx.x >> 4;
  const int s = blockIdx.x & 15;
  bool is1; int chbase;
  group_info(g, is1, chbase);
  const MP P = is1 ? p2 : p1;
  const int d = threadIdx.x;
  const float A = -__expf(P.A_log[d * DS_ + s]);
  float carry = 0.f, run = 0.f;
  for (int pc = 0; pc < GRP_; ++pc) {
    const size_t idx = (size_t)(chbase + pc);
    const float sdt = sumdt_g[idx * DI_ + d];
    const float hl = hloc[idx * DS_ * DI_ + s * DI_ + d];
    hloc[idx * DS_ * DI_ + s * DI_ + d] = carry;
    carry = __expf(A * sdt) * carry + hl;
    if (s == 0) presum_g[idx * DI_ + d] = run;
    run += sdt;
  }
  Sg[((size_t)g * DS_ + s) * DI_ + d] = carry;
  if (s == 0) gsum_g[(size_t)g * DI_ + d] = run;
}

// ---------------------------------------------------------------------------
// Scan pass 2b: chain the group summaries (<=16 per sequence). Overwrites Sg
// with the group's INCOMING carry Cg (read-before-write per slot).
// ---------------------------------------------------------------------------
__global__ __launch_bounds__(256) void k_scan2b(
    MP p1, MP p2, float* __restrict__ Sg,
    const float* __restrict__ gsum_g)
{
  const int seq = blockIdx.x >> 4;
  const int s = blockIdx.x & 15;
  const bool is1 = seq < 4;
  const int b = is1 ? seq : seq - 4;
  const MP P = is1 ? p2 : p1;
  const int ng = is1 ? NG1_ : NG2_;
  const int gbase = is1 ? b * NG1_ : 4 * NG1_ + b * NG2_;
  const int d = threadIdx.x;
  const float A = -__expf(P.A_log[d * DS_ + s]);
  float C = 0.f;
  for (int gi = 0; gi < ng; ++gi) {
    const int g = gbase + gi;
    const float gs = gsum_g[(size_t)g * DI_ + d];
    const float sgv = Sg[((size_t)g * DS_ + s) * DI_ + d];
    Sg[((size_t)g * DS_ + s) * DI_ + d] = C;
    C = __expf(A * gs) * C + sgv;
  }
}

// ---------------------------------------------------------------------------
// Scan pass 3: h_init = group-local carry (hloc) + Cg * exp(A*presum); replay
// chunk; emit v = (y + xc*D)*sz (bf16) IN PLACE over the silu(z) buffer.
// ---------------------------------------------------------------------------
__global__ __launch_bounds__(256) void k_scan3(
    MP p1, MP p2,
    const __hip_bfloat16* __restrict__ xc_g, const float* __restrict__ dbl_g,
    const float* __restrict__ hin, const float* __restrict__ Cg_g,
    const float* __restrict__ presum_g, __hip_bfloat16* zv_g)
{
  const int blk = blockIdx.x;
  bool is1; int b, pc;
  if (blk < 4 * NCH1_) { is1 = true; b = blk / NCH1_; pc = blk % NCH1_; }
  else { const int r = blk - 4 * NCH1_; is1 = false; b = r / NCH2_; pc = r % NCH2_; }
  const MP P = is1 ? p2 : p1;
  const int L = is1 ? L1_ : L2_;
  const bool rev = is1;
  const int slotbase = is1 ? b * L1_ : N1_ + b * L2_;
  const int d = threadIdx.x;
  ScanP sp; load_scanp(P, d, sp);
  const float Dp = P.Dp[d];
  const unsigned short* xcp = (const unsigned short*)xc_g;
  unsigned short* zvp = (unsigned short*)zv_g;
  // group of this chunk + global carry reconstruction
  const int g = (blk < 4 * NCH1_) ? (blk / GRP_) : (4 * NG1_ + (blk - 4 * NCH1_) / GRP_);
  const float ps = presum_g[(size_t)blk * DI_ + d];
  const float* cg = Cg_g + ((size_t)g * DS_) * DI_ + d;
  float h[DS_];
  const float* hi = hin + (size_t)blk * DS_ * DI_;
  if (sp.fast) {
    const float e1p = __expf(sp.A0 * ps);
    float m = e1p;
    #pragma unroll
    for (int s = 0; s < DS_; ++s) { h[s] = hi[s * DI_ + d] + cg[s * DI_] * m; m *= e1p; }
  } else {
    #pragma unroll
    for (int s = 0; s < DS_; ++s)
      h[s] = hi[s * DI_ + d] + cg[s * DI_] * __expf(sp.Av[s] * ps);
  }
  const int s0 = rev ? (L - (pc + 1) * TS_) : pc * TS_;
  const int dp = rev ? -1 : 1;
  int slot = slotbase + (rev ? (s0 + TS_ - 1) : s0);
  if (sp.fast) {
    float sz = bf2f(zvp[(size_t)slot * DI_ + d]);
    #pragma unroll 2
    for (int i = 0; i < TS_; ++i) {
      const int nslot = (i + 1 < TS_) ? slot + dp : slot;
      const float nsz = bf2f(zvp[(size_t)nslot * DI_ + d]);   // prefetch before store
      const float* dr = dbl_g + (size_t)slot * 40;
      const float4 q0 = *(const float4*)dr, q1 = *(const float4*)(dr + 4);
      const float u = bf2f(xcp[(size_t)slot * DI_ + d]);
      float4 Bv[4], Cv[4];
      #pragma unroll
      for (int j = 0; j < 4; ++j) {
        Bv[j] = *(const float4*)(dr + 8 + 4 * j);
        Cv[j] = *(const float4*)(dr + 24 + 4 * j);
      }
      const float dt = dt_from(q0, q1, sp);
      const float du = dt * u;
      const float e1 = __expf(dt * sp.A0);
      const float e2 = e1 * e1, e3 = e2 * e1, e4 = e2 * e2;
      float base = 1.f, y = 0.f;
      #pragma unroll
      for (int j = 0; j < 4; ++j) {
        const float m1 = base * e1, m2 = base * e2, m3 = base * e3, m4 = base * e4;
        h[4*j+0] = m1 * h[4*j+0] + du * Bv[j].x;  y += h[4*j+0] * Cv[j].x;
        h[4*j+1] = m2 * h[4*j+1] + du * Bv[j].y;  y += h[4*j+1] * Cv[j].y;
        h[4*j+2] = m3 * h[4*j+2] + du * Bv[j].z;  y += h[4*j+2] * Cv[j].z;
        h[4*j+3] = m4 * h[4*j+3] + du * Bv[j].w;  y += h[4*j+3] * Cv[j].w;
        base = m4;
      }
      zvp[(size_t)slot * DI_ + d] = f2bf((y + u * Dp) * sz);
      slot = nslot; sz = nsz;
    }
  } else {
    for (int i = 0; i < TS_; ++i) {
      const float* dr = dbl_g + (size_t)slot * 40;
      const float4 q0 = *(const float4*)dr, q1 = *(const float4*)(dr + 4);
      const float dt = dt_from(q0, q1, sp);
      const float u = bf2f(xcp[(size_t)slot * DI_ + d]);
      const float sz = bf2f(zvp[(size_t)slot * DI_ + d]);
      const float du = dt * u;
      float Bvv[16], Cvv[16];
      #pragma unroll
      for (int j = 0; j < 4; ++j) {
        *(float4*)&Bvv[4*j] = *(const float4*)(dr + 8 + 4*j);
        *(float4*)&Cvv[4*j] = *(const float4*)(dr + 24 + 4*j);
      }
      float y = 0.f;
      #pragma unroll
      for (int s = 0; s < DS_; ++s) {
        h[s] = __expf(dt * sp.Av[s]) * h[s] + du * Bvv[s];
        y += h[s] * Cvv[s];
      }
      zvp[(size_t)slot * DI_ + d] = f2bf((y + u * Dp) * sz);
      slot += dp;
    }
  }
}

// ---------------------------------------------------------------------------
// Final: out_proj MFMA (A-fragments straight from global); output LN; scatter.
// ---------------------------------------------------------------------------
constexpr int OB_ = 132;
__global__ __launch_bounds__(256) void k_final(
    const __hip_bfloat16* __restrict__ v_g, const int* __restrict__ o_all,
    const unsigned short* __restrict__ w16,
    const float* __restrict__ norm_g, const float* __restrict__ norm_b,
    const float* __restrict__ normb_g, const float* __restrict__ normb_b,
    float* __restrict__ out)
{
  const int blk = blockIdx.x;
  bool is1; int b, tile;
  if (blk < 4 * NTILE1_) { is1 = true; b = blk / NTILE1_; tile = blk % NTILE1_; }
  else { const int r = blk - 4 * NTILE1_; is1 = false; b = r / NTILE2_; tile = r % NTILE2_; }
  const unsigned short* W = w16 + (is1 ? OW2_OFF : OW1_OFF);
  const float* gg = is1 ? normb_g : norm_g;
  const float* gb = is1 ? normb_b : norm_b;
  const int slotbase = is1 ? b * L1_ : N1_ + b * L2_;
  const int t0 = tile * TA_;
  __shared__ float obuf[TA_ * OB_];          // 16896 B
  const int tid = threadIdx.x;
  const int lane = tid & 63, wv = tid >> 6;
  const int l15 = lane & 15, quad = lane >> 4;
  {
    const unsigned short* vp = (const unsigned short*)v_g + (size_t)(slotbase + t0) * DI_;
    f32x4 acc00 = (f32x4){0.f,0.f,0.f,0.f}, acc01 = acc00, acc10 = acc00, acc11 = acc00;
    #pragma unroll
    for (int t = 0; t < 8; ++t) {
      const short8 a0 = *(const short8*)(vp + (size_t)(l15) * DI_ + t * 32 + quad * 8);
      const short8 a1 = *(const short8*)(vp + (size_t)(16 + l15) * DI_ + t * 32 + quad * 8);
      const short8 b0 = *(const short8*)(W + (size_t)((wv) * 16 + l15) * DI_ + t * 32 + quad * 8);
      const short8 b1 = *(const short8*)(W + (size_t)((wv + 4) * 16 + l15) * DI_ + t * 32 + quad * 8);
      acc00 = __builtin_amdgcn_mfma_f32_16x16x32_bf16(a0, b0, acc00, 0, 0, 0);
      acc01 = __builtin_amdgcn_mfma_f32_16x16x32_bf16(a1, b0, acc01, 0, 0, 0);
      acc10 = __builtin_amdgcn_mfma_f32_16x16x32_bf16(a0, b1, acc10, 0, 0, 0);
      acc11 = __builtin_amdgcn_mfma_f32_16x16x32_bf16(a1, b1, acc11, 0, 0, 0);
    }
    const int col0 = wv * 16 + l15;
    const int col1 = (wv + 4) * 16 + l15;
    #pragma unroll
    for (int r = 0; r < 4; ++r) {
      obuf[(quad * 4 + r) * OB_ + col0] = acc00[r];
      obuf[(16 + quad * 4 + r) * OB_ + col0] = acc01[r];
      obuf[(quad * 4 + r) * OB_ + col1] = acc10[r];
      obuf[(16 + quad * 4 + r) * OB_ + col1] = acc11[r];
    }
  }
  __syncthreads();
  {
    for (int m = wv; m < TA_; m += 4) {
      float x0 = obuf[m * OB_ + lane], x1 = obuf[m * OB_ + lane + 64];
      float s = x0 + x1, q = x0 * x0 + x1 * x1;
      #pragma unroll
      for (int off = 32; off; off >>= 1) {
        s += __shfl_xor(s, off, 64);
        q += __shfl_xor(q, off, 64);
      }
      const float mu = s * (1.f / 128.f);
      const float rs = rsqrtf(q * (1.f / 128.f) - mu * mu + 1e-5f);
      const int orig = o_all[slotbase + t0 + m];
      float* orow = out + (size_t)(slotbase + orig) * DM_;
      orow[lane]      = (x0 - mu) * rs * gg[lane]      + gb[lane];
      orow[lane + 64] = (x1 - mu) * rs * gg[lane + 64] + gb[lane + 64];
    }
  }
}

// ---------------------------------------------------------------------------
extern "C" void kernel_launch(void* const* d_in, const int* in_sizes, int n_in,
                              void* d_out, int out_size, void* d_ws, size_t ws_size,
                              hipStream_t stream)
{
  (void)in_sizes; (void)n_in; (void)out_size; (void)ws_size;
  const float* feats1 = (const float*)d_in[0];
  const float* feats2 = (const float*)d_in[1];
  const float* pos1   = (const float*)d_in[2];
  const float* pos2   = (const float*)d_in[3];
  const int*   hil1   = (const int*)d_in[4];
  const int*   hil2   = (const int*)d_in[5];
  const float* pe_w   = (const float*)d_in[6];
  const float* pe_b   = (const float*)d_in[7];
  const float* norm_g  = (const float*)d_in[8];
  const float* norm_b  = (const float*)d_in[9];
  const float* normb_g = (const float*)d_in[10];
  const float* normb_b = (const float*)d_in[11];
  MP p1 { (const float*)d_in[12], (const float*)d_in[13], (const float*)d_in[14],
          (const float*)d_in[15], (const float*)d_in[16], (const float*)d_in[17],
          (const float*)d_in[18], (const float*)d_in[19], (const float*)d_in[20],
          (const float*)d_in[21], (const float*)d_in[22] };
  MP p2 { (const float*)d_in[23], (const float*)d_in[24], (const float*)d_in[25],
          (const float*)d_in[26], (const float*)d_in[27], (const float*)d_in[28],
          (const float*)d_in[29], (const float*)d_in[30], (const float*)d_in[31],
          (const float*)d_in[32], (const float*)d_in[33] };

  char* w = (char*)d_ws;
  auto take = [&](size_t bytes) -> char* {
    char* p = w; w += (bytes + 255) & ~(size_t)255; return p;
  };
  int* o_all = (int*)take((size_t)TOT_ * 4);
  // Union region (42 MB): (a) radix-sort temporaries (live during sort only),
  // (b) padded seq buffer (written by k_gather, read by k_phaseA),
  // (c) Sg/presum/gsum for hierarchical scan2 (written after phaseA).
  char* uni = take((size_t)RTOT_ * DM_ * 2);
  unsigned* kA = (unsigned*)(uni);
  int*      iA = (int*)     (uni + (size_t)TOT_ * 4);
  unsigned* kB = (unsigned*)(uni + (size_t)TOT_ * 8);
  int*      iB = (int*)     (uni + (size_t)TOT_ * 12);
  unsigned* histg = (unsigned*)(uni + (size_t)TOT_ * 16);
  unsigned* offg  = (unsigned*)(uni + (size_t)TOT_ * 16 + (size_t)NST_ * 1024 * 4);
  unsigned* seq = (unsigned*)uni;              // padded bf16 rows (after sort)
  float* Sg     = (float*)uni;                                    // 5.24 MB (after phaseA)
  float* presum = (float*)(uni + (size_t)NGRPS_ * DS_ * DI_ * 4); // 2.62 MB
  float* gsum   = (float*)(uni + (size_t)NGRPS_ * DS_ * DI_ * 4
                               + (size_t)NCHUNKS_ * DI_ * 4);     // 82 KB
  __hip_bfloat16* xc = (__hip_bfloat16*)take((size_t)TOT_ * DI_ * 2);
  __hip_bfloat16* vzb = (__hip_bfloat16*)take((size_t)TOT_ * DI_ * 2);  // silu(z), then v
  float* dbl = (float*)take((size_t)TOT_ * 40 * 4);
  float* hloc = (float*)take((size_t)NCHUNKS_ * DS_ * DI_ * 4);  // local states, then carry-in (in place)
  float* sdt  = (float*)take((size_t)NCHUNKS_ * DI_ * 4);
  unsigned short* w16 = (unsigned short*)take((size_t)W16_TOT * 2);

  hipLaunchKernelGGL(k_prep, dim3((W16_TOT + 255) / 256), dim3(256), 0, stream,
                     p1.in_w, p1.xproj_w, p1.out_w, p2.in_w, p2.xproj_w, p2.out_w, w16);
  // radix sort: 3 passes of (hist, scan, scatter)
  hipLaunchKernelGGL(k_hist, dim3(NST_), dim3(256), 0, stream,
                     hil1, hil2, kB, histg, 0, 1);
  hipLaunchKernelGGL(k_scanoff, dim3(8), dim3(256), 0, stream, histg, offg);
  hipLaunchKernelGGL(k_scatter, dim3(NST_), dim3(256), 0, stream,
                     hil1, hil2, kB, iB, offg, kB, iB, o_all, 0, 1, 0);
  hipLaunchKernelGGL(k_hist, dim3(NST_), dim3(256), 0, stream,
                     hil1, hil2, kB, histg, 10, 0);
  hipLaunchKernelGGL(k_scanoff, dim3(8), dim3(256), 0, stream, histg, offg);
  hipLaunchKernelGGL(k_scatter, dim3(NST_), dim3(256), 0, stream,
                     hil1, hil2, kB, iB, offg, kA, iA, o_all, 10, 0, 0);
  hipLaunchKernelGGL(k_hist, dim3(NST_), dim3(256), 0, stream,
                     hil1, hil2, kA, histg, 20, 0);
  hipLaunchKernelGGL(k_scanoff, dim3(8), dim3(256), 0, stream, histg, offg);
  hipLaunchKernelGGL(k_scatter, dim3(NST_), dim3(256), 0, stream,
                     hil1, hil2, kA, iA, offg, kB, iB, o_all, 20, 0, 1);

  hipLaunchKernelGGL(k_gather, dim3((RTOT_ + 3) / 4), dim3(256), 0, stream,
                     feats1, feats2, pos1, pos2, pe_w, pe_b, p1, p2, o_all, seq);
  hipLaunchKernelGGL(k_phaseA, dim3(NTILES_), dim3(256), 0, stream,
                     p1, p2, (const unsigned short*)seq, w16, xc, vzb, dbl);
  hipLaunchKernelGGL(k_scan1, dim3(NCHUNKS_), dim3(256), 0, stream,
                     p1, p2, xc, dbl, hloc, sdt);
  hipLaunchKernelGGL(k_scan2a, dim3(NGRPS_ * DS_), dim3(256), 0, stream,
                     p1, p2, hloc, sdt, Sg, presum, gsum);
  hipLaunchKernelGGL(k_scan2b, dim3(128), dim3(256), 0, stream,
                     p1, p2, Sg, gsum);
  hipLaunchKernelGGL(k_scan3, dim3(NCHUNKS_), dim3(256), 0, stream,
                     p1, p2, xc, dbl, hloc, Sg, presum, vzb);
  hipLaunchKernelGGL(k_final, dim3(NTILES_), dim3(256), 0, stream,
                     vzb, o_all, w16, norm_g, norm_b, normb_g, normb_b,
                     (float*)d_out);
}